// Round 4
// baseline (403.665 us; speedup 1.0000x reference)
//
#include <hip/hip_runtime.h>

typedef __attribute__((ext_vector_type(8))) short short8;
typedef __attribute__((ext_vector_type(4))) float floatx4;

#define MFMA16(a, b, c) __builtin_amdgcn_mfma_f32_16x16x32_bf16(a, b, c, 0, 0, 0)

__device__ __forceinline__ short f2bf(float f) {
    unsigned int u = __float_as_uint(f);
    u = u + 0x7fffu + ((u >> 16) & 1u);
    return (short)(u >> 16);
}

__device__ __forceinline__ void ldst16(const void* g, void* l) {
    __builtin_amdgcn_global_load_lds(
        (const __attribute__((address_space(1))) void*)g,
        (__attribute__((address_space(3))) void*)l, 16, 0, 0);
}

// ---------------------------------------------------------------------------
// Kernel 0: convert Wq/Wk/Wv fp32 [1024][128] -> bf16 transposed [128][1024]
// ---------------------------------------------------------------------------
__global__ __launch_bounds__(256) void wconv_kernel(const float* __restrict__ Wq,
                                                    const float* __restrict__ Wk,
                                                    const float* __restrict__ Wv,
                                                    short* __restrict__ wt) {
    int idx = blockIdx.x * 256 + threadIdx.x;   // < 3*131072
    int w = idx >> 17;
    int rem = idx & 131071;
    int k = rem >> 7, n = rem & 127;
    const float* W = (w == 0) ? Wq : (w == 1) ? Wk : Wv;
    wt[w * 131072 + n * 1024 + k] = f2bf(W[rem]);
}

// ---------------------------------------------------------------------------
// Kernel 1 (fused q/k/v): C = A[16384x1024](f32) * W (+bias) -> bf16.
// r0-r3 post-mortem: all K-chunked variants pinned at ~100 µs (256B-granular
// row walks + per-chunk barrier/vmcnt drains). v4: stage 16 FULL A rows
// (4 KB contiguous each, 64 KB LDS) in ONE shot, ONE barrier per block,
// then compute entirely from LDS + L2-resident W (direct loads; no
// background DMA left to be poisoned by in-order vmcnt). Block 256 thr =
// 4 waves, each 16 rows x 32 cols. Grid (1024,3), 2 blocks/CU -> >=128 KB
// of contiguous HBM reads in flight per CU at all times.
// ---------------------------------------------------------------------------
__global__ __launch_bounds__(256, 2) void proj_kernel(const float* __restrict__ Q,
                                                      const float* __restrict__ K,
                                                      const float* __restrict__ V,
                                                      const short* __restrict__ wt,
                                                      const float* __restrict__ bq,
                                                      const float* __restrict__ bk,
                                                      const float* __restrict__ bv,
                                                      short* __restrict__ qo,
                                                      short* __restrict__ ko,
                                                      short* __restrict__ vo) {
    alignas(16) __shared__ float Asl[16 * 1024];  // 64 KB: [row][256 slots], pos=c^(row&15)
    const int t = threadIdx.x;                    // 0..255
    const int wvid = t >> 6, L = t & 63;
    const int q4 = L >> 4, l16 = L & 15;
    const int wc = wvid;                          // wave's col group (32 cols)
    const int which = blockIdx.y;
    const float* A = (which == 0) ? Q : (which == 1) ? K : V;
    const short* Wt = wt + which * 131072;
    const float* bias = (which == 0) ? bq : (which == 1) ? bk : bv;
    const int m0 = blockIdx.x * 16;               // block's 16 rows

    // stage: 16 rows x 4 KB, row-linear from HBM. Source col pre-swizzled
    // (dest is linear: slot s = j*256 + t), so LDS[r][p] = A[r][(p^(r&15))*4..]
#pragma unroll
    for (int j = 0; j < 16; j++) {
        ldst16(A + (size_t)(m0 + j) * 1024 + ((t ^ (j & 15)) << 2),
               Asl + (j * 256 + 64 * wvid) * 4);
    }
    __syncthreads();                              // ONE drain per block

    floatx4 acc[2];
    acc[0] = (floatx4)0.0f;
    acc[1] = (floatx4)0.0f;

    // B-frag: lane(q4,l16) holds Wt[col=32*wc+16*nt+l16][32*ks + 8*q4 + e]
    const short* wb = Wt + (size_t)(32 * wc + l16) * 1024 + 8 * q4;

    for (int ks = 0; ks < 32; ks++) {
        // A-frag: lane(q4,l16) holds A[row=l16][k=32*ks+8*q4+e]
        int c0 = 8 * ks + 2 * q4;
        float4 f0 = *(float4*)&Asl[(l16 * 256 + (c0 ^ l16)) * 4];
        float4 f1 = *(float4*)&Asl[(l16 * 256 + ((c0 + 1) ^ l16)) * 4];
        short8 af;
        af[0] = f2bf(f0.x); af[1] = f2bf(f0.y); af[2] = f2bf(f0.z); af[3] = f2bf(f0.w);
        af[4] = f2bf(f1.x); af[5] = f2bf(f1.y); af[6] = f2bf(f1.z); af[7] = f2bf(f1.w);
#pragma unroll
        for (int nt = 0; nt < 2; nt++) {
            short8 bf = *(const short8*)(wb + (size_t)nt * 16384 + 32 * ks);
            acc[nt] = MFMA16(af, bf, acc[nt]);
        }
    }

    const int rbase = m0 + q4 * 4;                // C/D: row=(lane>>4)*4+r
#pragma unroll
    for (int nt = 0; nt < 2; nt++) {
        const int col = 32 * wc + 16 * nt + l16;  // C/D: col=lane&15
        float bvv = bias[col];
#pragma unroll
        for (int r = 0; r < 4; r++) {
            short h = f2bf(acc[nt][r] + bvv);
            int grow = rbase + r;
            if (which == 0) {
                qo[(size_t)grow * 128 + col] = h;
            } else if (which == 1) {
                ko[(size_t)grow * 128 + col] = h;
            } else {
                int bb = grow >> 11, s = grow & 2047;
                vo[(size_t)bb * 262144 + (size_t)col * 2048 + s] = h;
            }
        }
    }
}

// ---------------------------------------------------------------------------
// Kernel 2: flash attention, fixed-offset softmax (scores bounded; see r0).
// v4: K/V are L2-resident (1 MB per batch, reused by 64 blocks) -> NO LDS
// staging at all (Common-mistake #7). K and V fragments load DIRECT
// global->VGPR (formulas == the staged-swizzle reads). Zero barriers in
// the kv loop; waves fully independent until the final merge. kv split
// 4-way: block = 512 thr = 4 quarters x 2 waves, q-tile 32, grid 512 =
// 2 blocks/CU = 16 waves/CU for L2-latency hiding. Batch->XCD swizzle
// (b = bid & 7): each XCD's L2 caches exactly one batch's K/V.
// LDS: P-transpose 18.4 KB, merge region 48.5 KB (union, Pl dead by then).
// ---------------------------------------------------------------------------
__global__ __launch_bounds__(512, 3) void flash_kernel(const short* __restrict__ qw,
                                                       const short* __restrict__ kw,
                                                       const short* __restrict__ vw,
                                                       float* __restrict__ out) {
    union SMem {
        short Pl[4][32][72];                        // [quarter][q-row][kv] (+8 pad)
        struct { float Om[3][32][128]; float Lm[3][32]; } m;
    };
    alignas(16) __shared__ SMem sm;
    const int t = threadIdx.x;                      // 0..511
    const int wvi = t >> 6, L = t & 63;
    const int qr = wvi >> 1, wq = wvi & 1;          // kv-quarter, wave-in-quarter
    const int q4 = L >> 4, l16 = L & 15;
    const int bid = blockIdx.x;
    const int b = bid & 7, bq = bid >> 3;           // batch->XCD affinity
    const short* qp = qw + (size_t)b * 262144 + (size_t)bq * 32 * 128;
    const short* kp = kw + (size_t)b * 262144;
    const short* vp = vw + (size_t)b * 262144;

    // Q-frags: wave-private, direct from global (row = 16*wq + l16)
    short8 qf[4];
#pragma unroll
    for (int ks = 0; ks < 4; ks++)
        qf[ks] = *(const short8*)(qp + (16 * wq + l16) * 128 + ks * 32 + q4 * 8);

    floatx4 oacc[8];
#pragma unroll
    for (int dt = 0; dt < 8; dt++) oacc[dt] = (floatx4)0.0f;
    float ps[4] = {0.f, 0.f, 0.f, 0.f};             // distributed row sums
    const float SL = (float)(0.08838834764831845 * 1.4426950408889634); // 1/sqrt(128)*log2(e)

    // per-lane base pointers for direct fragment loads
    const short* kb = kp + (size_t)l16 * 128 + 8 * q4;   // + (kv+16nt)*128 + 32ks
    const short* vb = vp + (size_t)l16 * 2048 + 8 * q4;  // + 16dt*2048 + kv0 (+32)

    for (int kt = 0; kt < 8; kt++) {
        const int kv0 = qr * 512 + kt * 64;

        // S = Q K^T  (16 q-rows x 64 kv per wave), K direct from L2
        floatx4 sa[4];
#pragma unroll
        for (int nt = 0; nt < 4; nt++) {
            sa[nt] = (floatx4)0.0f;
#pragma unroll
            for (int ks = 0; ks < 4; ks++) {
                short8 bfr = *(const short8*)(kb + (size_t)(kv0 + 16 * nt) * 128 + 32 * ks);
                sa[nt] = MFMA16(qf[ks], bfr, sa[nt]);
            }
        }

        // fixed-offset softmax: p = exp2(s*SL - 4); accumulate per-lane sums
#pragma unroll
        for (int nt = 0; nt < 4; nt++) {
#pragma unroll
            for (int r = 0; r < 4; r++) {
                float pv = __builtin_amdgcn_exp2f(sa[nt][r] * SL - 4.0f);
                ps[r] += pv;
                sm.Pl[qr][16 * wq + q4 * 4 + r][16 * nt + l16] = f2bf(pv);
            }
        }

        // O += P V   (V fragments direct from L2, pre-transposed vt[d][s])
        short8 pf0 = *(short8*)&sm.Pl[qr][16 * wq + l16][q4 * 8];
        short8 pf1 = *(short8*)&sm.Pl[qr][16 * wq + l16][32 + q4 * 8];
#pragma unroll
        for (int dt = 0; dt < 8; dt++) {
            short8 v0 = *(const short8*)(vb + (size_t)(16 * dt) * 2048 + kv0);
            short8 v1 = *(const short8*)(vb + (size_t)(16 * dt) * 2048 + kv0 + 32);
            oacc[dt] = MFMA16(pf0, v0, oacc[dt]);
            oacc[dt] = MFMA16(pf1, v1, oacc[dt]);
        }
    }

    // sum ps over the 16 col-lanes per row group
#pragma unroll
    for (int r = 0; r < 4; r++)
#pragma unroll
        for (int off = 1; off <= 8; off <<= 1)
            ps[r] += __shfl_xor(ps[r], off, 64);

    // ---- 4-way merge of kv-quarters (plain sums; no max needed) ----
    __syncthreads();                                // Pl dead; union -> merge region
    if (qr > 0) {
#pragma unroll
        for (int dt = 0; dt < 8; dt++)
#pragma unroll
            for (int r = 0; r < 4; r++)
                sm.m.Om[qr - 1][16 * wq + q4 * 4 + r][16 * dt + l16] = oacc[dt][r];
        if (l16 == 0)
#pragma unroll
            for (int r = 0; r < 4; r++)
                sm.m.Lm[qr - 1][16 * wq + q4 * 4 + r] = ps[r];
    }
    __syncthreads();
    if (qr == 0) {
        float inv[4];
#pragma unroll
        for (int r = 0; r < 4; r++) {
            int row = 16 * wq + q4 * 4 + r;
            inv[r] = 1.0f / (ps[r] + sm.m.Lm[0][row] + sm.m.Lm[1][row] + sm.m.Lm[2][row]);
        }
#pragma unroll
        for (int dt = 0; dt < 8; dt++) {
#pragma unroll
            for (int r = 0; r < 4; r++) {
                int row = 16 * wq + q4 * 4 + r;
                int c = 16 * dt + l16;
                float v = oacc[dt][r] + sm.m.Om[0][row][c] + sm.m.Om[1][row][c] + sm.m.Om[2][row][c];
                int qrow = bq * 32 + row;
                out[((size_t)b * 2048 + qrow) * 128 + c] = v * inv[r];
            }
        }
    }
}

extern "C" void kernel_launch(void* const* d_in, const int* in_sizes, int n_in,
                              void* d_out, int out_size, void* d_ws, size_t ws_size,
                              hipStream_t stream) {
    const float* query = (const float*)d_in[0];
    const float* key   = (const float*)d_in[1];
    const float* value = (const float*)d_in[2];
    const float* Wq    = (const float*)d_in[3];
    const float* bq    = (const float*)d_in[4];
    const float* Wk    = (const float*)d_in[5];
    const float* bk    = (const float*)d_in[6];
    const float* Wv    = (const float*)d_in[7];
    const float* bv    = (const float*)d_in[8];
    float* out = (float*)d_out;

    // ws layout (shorts): Wt[3][128][1024] | q[16384][128] | k[16384][128] | vt[8][128][2048]
    short* wt  = (short*)d_ws;
    short* qws = wt + 3 * 131072;
    short* kws = qws + 16384 * 128;
    short* vws = kws + 16384 * 128;

    wconv_kernel<<<1536, 256, 0, stream>>>(Wq, Wk, Wv, wt);
    proj_kernel<<<dim3(1024, 3), 256, 0, stream>>>(query, key, value, wt,
                                                   bq, bk, bv, qws, kws, vws);
    flash_kernel<<<512, 512, 0, stream>>>(qws, kws, vws, out);
}

// Round 5
// 291.199 us; speedup vs baseline: 1.3862x; 1.3862x over previous
//
#include <hip/hip_runtime.h>

typedef __attribute__((ext_vector_type(8))) short short8;
typedef __attribute__((ext_vector_type(4))) float floatx4;

#define MFMA16(a, b, c) __builtin_amdgcn_mfma_f32_16x16x32_bf16(a, b, c, 0, 0, 0)

__device__ __forceinline__ short f2bf(float f) {
    unsigned int u = __float_as_uint(f);
    u = u + 0x7fffu + ((u >> 16) & 1u);
    return (short)(u >> 16);
}

__device__ __forceinline__ void ldst16(const void* g, void* l) {
    __builtin_amdgcn_global_load_lds(
        (const __attribute__((address_space(1))) void*)g,
        (__attribute__((address_space(3))) void*)l, 16, 0, 0);
}

// ---------------------------------------------------------------------------
// Kernel 0: convert Wq/Wk/Wv fp32 [1024][128] -> bf16 transposed [128][1024]
// ---------------------------------------------------------------------------
__global__ __launch_bounds__(256) void wconv_kernel(const float* __restrict__ Wq,
                                                    const float* __restrict__ Wk,
                                                    const float* __restrict__ Wv,
                                                    short* __restrict__ wt) {
    int idx = blockIdx.x * 256 + threadIdx.x;   // < 3*131072
    int w = idx >> 17;
    int rem = idx & 131071;
    int k = rem >> 7, n = rem & 127;
    const float* W = (w == 0) ? Wq : (w == 1) ? Wk : Wv;
    wt[w * 131072 + n * 1024 + k] = f2bf(W[rem]);
}

// ---------------------------------------------------------------------------
// Kernel 1 (fused q/k/v): C = A[16384x1024](f32) * W (+bias) -> bf16.
// r3/r4 lesson: direct global fragment gathers (16 lines/instr) are the
// poison; ALL fragments must come from LDS via coalesced DMA (r0 was right).
// v5 = r0 + (a) BM=128 so W staging amortizes 4x (DMA 590->300 MB), (b)
// double-buffered chunks, ONE barrier per chunk, stage(k+1) issued right
// after the barrier and landing under compute(k) (compute touches no global
// loads -> nothing for in-order vmcnt to poison). BK=32: A 16KB + W 8KB per
// buffer, 48KB total -> 3 blocks/CU, grid (128,3)=384 all co-resident.
// 256 thr = 2x2 waves, each 64 rows x 64 cols (16 MFMA/chunk/wave).
// ---------------------------------------------------------------------------
__global__ __launch_bounds__(256, 3) void proj_kernel(const float* __restrict__ Q,
                                                      const float* __restrict__ K,
                                                      const float* __restrict__ V,
                                                      const short* __restrict__ wt,
                                                      const float* __restrict__ bq,
                                                      const float* __restrict__ bk,
                                                      const float* __restrict__ bv,
                                                      short* __restrict__ qo,
                                                      short* __restrict__ ko,
                                                      short* __restrict__ vo) {
    alignas(16) __shared__ float Asl[2][128 * 32];  // 16KB/buf: [row][8 slots], pos=c^(r&7)
    alignas(16) __shared__ short Wsl[2][128 * 32];  // 8KB/buf:  [col][4 slots], linear (2-way free)
    const int t = threadIdx.x;                    // 0..255
    const int wv = t >> 6, L = t & 63;
    const int wm = wv >> 1, wn = wv & 1;          // 2x2 wave grid
    const int q4 = L >> 4, l16 = L & 15;
    const int which = blockIdx.y;
    const float* A = (which == 0) ? Q : (which == 1) ? K : V;
    const short* Wt = wt + which * 131072;
    const float* bias = (which == 0) ? bq : (which == 1) ? bk : bv;
    const int m0 = blockIdx.x * 128;

    floatx4 acc[4][4];
#pragma unroll
    for (int rg = 0; rg < 4; rg++)
#pragma unroll
        for (int nt = 0; nt < 4; nt++) acc[rg][nt] = (floatx4)0.0f;

    auto stage = [&](int buf, int k0) {
        // A tile 128x32 f32 = 1024 slots16 / 256 thr = 4 issues.
        // Dest linear (slot s), source col pre-swizzled: LDS[r][c] = A[r][(c^(r&7))*4..]
#pragma unroll
        for (int j = 0; j < 4; j++) {
            int s = j * 256 + t;
            int r = s >> 3, c = s & 7;
            ldst16(A + (size_t)(m0 + r) * 1024 + k0 + ((c ^ (r & 7)) << 2),
                   &Asl[buf][(j * 256 + 64 * wv) * 4]);
        }
        // W tile 128x32 bf16 = 512 slots16 / 256 thr = 2 issues, linear.
#pragma unroll
        for (int j = 0; j < 2; j++) {
            int s = j * 256 + t;
            int r = s >> 2, c = s & 3;
            ldst16(Wt + (size_t)r * 1024 + k0 + c * 8,
                   &Wsl[buf][(j * 256 + 64 * wv) * 8]);
        }
    };

    stage(0, 0);                                  // prologue DMA

    for (int kc = 0; kc < 32; kc++) {
        const int cur = kc & 1;
        __syncthreads();                          // drains stage(kc); prev compute done
        if (kc + 1 < 32) stage(cur ^ 1, (kc + 1) * 32);  // next chunk lands under compute

        // A-frags: lane(q4,l16) holds A[row][k=8*q4+e], e=0..7
        short8 af[4];
#pragma unroll
        for (int rg = 0; rg < 4; rg++) {
            int r = 64 * wm + 16 * rg + l16;
            float4 f0 = *(float4*)&Asl[cur][r * 32 + ((2 * q4) ^ (r & 7)) * 4];
            float4 f1 = *(float4*)&Asl[cur][r * 32 + ((2 * q4 + 1) ^ (r & 7)) * 4];
            short8 v;
            v[0] = f2bf(f0.x); v[1] = f2bf(f0.y); v[2] = f2bf(f0.z); v[3] = f2bf(f0.w);
            v[4] = f2bf(f1.x); v[5] = f2bf(f1.y); v[6] = f2bf(f1.z); v[7] = f2bf(f1.w);
            af[rg] = v;
        }
#pragma unroll
        for (int nt = 0; nt < 4; nt++) {
            int col = 64 * wn + 16 * nt + l16;
            short8 bf = *(short8*)&Wsl[cur][col * 32 + q4 * 8];
#pragma unroll
            for (int rg = 0; rg < 4; rg++)
                acc[rg][nt] = MFMA16(af[rg], bf, acc[rg][nt]);
        }
    }

#pragma unroll
    for (int rg = 0; rg < 4; rg++) {
        const int rbase = m0 + 64 * wm + 16 * rg + q4 * 4;  // C/D: row=(lane>>4)*4+r
#pragma unroll
        for (int nt = 0; nt < 4; nt++) {
            const int col = 64 * wn + 16 * nt + l16;        // C/D: col=lane&15
            float bvv = bias[col];
#pragma unroll
            for (int r = 0; r < 4; r++) {
                short h = f2bf(acc[rg][nt][r] + bvv);
                int grow = rbase + r;
                if (which == 0) {
                    qo[(size_t)grow * 128 + col] = h;
                } else if (which == 1) {
                    ko[(size_t)grow * 128 + col] = h;
                } else {
                    int bb = grow >> 11, s = grow & 2047;
                    vo[(size_t)bb * 262144 + (size_t)col * 2048 + s] = h;
                }
            }
        }
    }
}

// ---------------------------------------------------------------------------
// Kernel 2: flash attention, fixed-offset softmax (scores bounded; see r0).
// v5 = r0's staged-fragment structure (the fast path) minus its two
// weaknesses: serial kv per wave (no pair split -> NO merge phase) and
// double-buffered K/V with one barrier/iter (stage(t+1) lands under
// compute(t)). 256 thr = 4 waves, wave w owns q-rows [16w,16w+16), kv walk
// 32 iters of 64. LDS 73.2KB (2x16KB K + 2x16KB V + 9.2KB P) -> 2
// blocks/CU = 8 waves/CU. Grid 256 = (32 q-tiles x 8 batches), batch->XCD
// swizzle so each XCD's L2 holds one batch's 1MB of K/V.
// ---------------------------------------------------------------------------
__global__ __launch_bounds__(256, 2) void flash_kernel(const short* __restrict__ qw,
                                                       const short* __restrict__ kw,
                                                       const short* __restrict__ vw,
                                                       float* __restrict__ out) {
    alignas(16) __shared__ short Kls[2][64 * 128];   // [buf], pos=c^(r&15)
    alignas(16) __shared__ short Vls[2][128 * 64];   // [buf], pos=c^(r&7)
    alignas(16) __shared__ short Pl[4][16][72];      // [wave][q][kv] (+8 pad)
    const int t = threadIdx.x;                       // 0..255
    const int w = t >> 6, L = t & 63;
    const int q4 = L >> 4, l16 = L & 15;
    const int bid = blockIdx.x;
    const int b = bid & 7, bq = bid >> 3;            // batch->XCD affinity
    const short* qp = qw + (size_t)b * 262144 + (size_t)bq * 64 * 128;
    const short* kp = kw + (size_t)b * 262144;
    const short* vp = vw + (size_t)b * 262144;

    // Q-frags: wave-private, direct from global (row = 16*w + l16), read once
    short8 qf[4];
#pragma unroll
    for (int ks = 0; ks < 4; ks++)
        qf[ks] = *(const short8*)(qp + (16 * w + l16) * 128 + ks * 32 + q4 * 8);

    floatx4 oacc[8];
#pragma unroll
    for (int dt = 0; dt < 8; dt++) oacc[dt] = (floatx4)0.0f;
    float ps[4] = {0.f, 0.f, 0.f, 0.f};              // distributed row sums
    const float SL = (float)(0.08838834764831845 * 1.4426950408889634); // 1/sqrt(128)*log2(e)

    auto stage = [&](int buf, int kt) {
        const int kv0 = kt * 64;
        // K-tile 64x128 (16KB): 1024 slots16 / 256 thr = 4 issues
#pragma unroll
        for (int j = 0; j < 4; j++) {
            int s = j * 256 + t;
            int r = s >> 4, c = (s & 15) ^ (r & 15);
            ldst16(kp + (size_t)(kv0 + r) * 128 + c * 8,
                   &Kls[buf][(j * 256 + 64 * w) * 8]);
        }
        // V-tile 128x64 (pre-transposed vt): 1024 slots16 / 256 thr
#pragma unroll
        for (int j = 0; j < 4; j++) {
            int s = j * 256 + t;
            int r = s >> 3, c = (s & 7) ^ (r & 7);
            ldst16(vp + (size_t)r * 2048 + kv0 + c * 8,
                   &Vls[buf][(j * 256 + 64 * w) * 8]);
        }
    };

    stage(0, 0);                                     // prologue DMA

    for (int kt = 0; kt < 32; kt++) {
        const int cur = kt & 1;
        __syncthreads();   // drains stage(kt); all waves done reading buf cur^1
        if (kt + 1 < 32) stage(cur ^ 1, kt + 1);     // next-tile DMA under compute

        // S = Q K^T  (16 q-rows x 64 kv per wave)
        floatx4 sa[4];
#pragma unroll
        for (int nt = 0; nt < 4; nt++) {
            sa[nt] = (floatx4)0.0f;
#pragma unroll
            for (int ks = 0; ks < 4; ks++) {
                short8 bfr = *(short8*)&Kls[cur][(16 * nt + l16) * 128 + ((4 * ks + q4) ^ l16) * 8];
                sa[nt] = MFMA16(qf[ks], bfr, sa[nt]);
            }
        }

        // fixed-offset softmax: p = exp2(s*SL - 4); accumulate per-lane sums
#pragma unroll
        for (int nt = 0; nt < 4; nt++) {
#pragma unroll
            for (int r = 0; r < 4; r++) {
                float pv = __builtin_amdgcn_exp2f(sa[nt][r] * SL - 4.0f);
                ps[r] += pv;
                Pl[w][q4 * 4 + r][16 * nt + l16] = f2bf(pv);
            }
        }

        // O += P V (wave-private P round-trip through LDS for the transpose)
        short8 pf0 = *(short8*)&Pl[w][l16][q4 * 8];
        short8 pf1 = *(short8*)&Pl[w][l16][32 + q4 * 8];
#pragma unroll
        for (int dt = 0; dt < 8; dt++) {
            short8 v0 = *(short8*)&Vls[cur][(16 * dt + l16) * 64 + (q4 ^ (l16 & 7)) * 8];
            short8 v1 = *(short8*)&Vls[cur][(16 * dt + l16) * 64 + ((4 + q4) ^ (l16 & 7)) * 8];
            oacc[dt] = MFMA16(pf0, v0, oacc[dt]);
            oacc[dt] = MFMA16(pf1, v1, oacc[dt]);
        }
    }

    // each wave saw the FULL kv range: reduce ps across the 16 col-lanes, done
#pragma unroll
    for (int r = 0; r < 4; r++)
#pragma unroll
        for (int off = 1; off <= 8; off <<= 1)
            ps[r] += __shfl_xor(ps[r], off, 64);

    float inv[4];
#pragma unroll
    for (int r = 0; r < 4; r++) inv[r] = 1.0f / ps[r];
#pragma unroll
    for (int dt = 0; dt < 8; dt++) {
#pragma unroll
        for (int r = 0; r < 4; r++) {
            int row = 16 * w + q4 * 4 + r;
            int qrow = bq * 64 + row;
            out[((size_t)b * 2048 + qrow) * 128 + 16 * dt + l16] = oacc[dt][r] * inv[r];
        }
    }
}

extern "C" void kernel_launch(void* const* d_in, const int* in_sizes, int n_in,
                              void* d_out, int out_size, void* d_ws, size_t ws_size,
                              hipStream_t stream) {
    const float* query = (const float*)d_in[0];
    const float* key   = (const float*)d_in[1];
    const float* value = (const float*)d_in[2];
    const float* Wq    = (const float*)d_in[3];
    const float* bq    = (const float*)d_in[4];
    const float* Wk    = (const float*)d_in[5];
    const float* bk    = (const float*)d_in[6];
    const float* Wv    = (const float*)d_in[7];
    const float* bv    = (const float*)d_in[8];
    float* out = (float*)d_out;

    // ws layout (shorts): Wt[3][128][1024] | q[16384][128] | k[16384][128] | vt[8][128][2048]
    short* wt  = (short*)d_ws;
    short* qws = wt + 3 * 131072;
    short* kws = qws + 16384 * 128;
    short* vws = kws + 16384 * 128;

    wconv_kernel<<<1536, 256, 0, stream>>>(Wq, Wk, Wv, wt);
    proj_kernel<<<dim3(128, 3), 256, 0, stream>>>(query, key, value, wt,
                                                  bq, bk, bv, qws, kws, vws);
    flash_kernel<<<256, 256, 0, stream>>>(qws, kws, vws, out);
}

// Round 6
// 261.337 us; speedup vs baseline: 1.5446x; 1.1143x over previous
//
#include <hip/hip_runtime.h>

typedef __attribute__((ext_vector_type(8))) short short8;
typedef __attribute__((ext_vector_type(4))) float floatx4;

#define MFMA16(a, b, c) __builtin_amdgcn_mfma_f32_16x16x32_bf16(a, b, c, 0, 0, 0)

__device__ __forceinline__ short f2bf(float f) {
    unsigned int u = __float_as_uint(f);
    u = u + 0x7fffu + ((u >> 16) & 1u);
    return (short)(u >> 16);
}

__device__ __forceinline__ void ldst16(const void* g, void* l) {
    __builtin_amdgcn_global_load_lds(
        (const __attribute__((address_space(1))) void*)g,
        (__attribute__((address_space(3))) void*)l, 16, 0, 0);
}

// ---------------------------------------------------------------------------
// Kernel 0: convert Wq/Wk/Wv fp32 [1024][128] -> bf16 in MFMA FRAGMENT ORDER:
// wtf[which][ks(32)][nt(8)][lane(64)][e(8)], value = W[k][n] with
// n = 16*nt + (lane&15), k = 32*ks + 8*(lane>>4) + e.  A wave's B-fragment
// load is then ONE coalesced 1KB block (base + lane*16B): no gather, no LDS.
// ---------------------------------------------------------------------------
__global__ __launch_bounds__(256) void wconv_kernel(const float* __restrict__ Wq,
                                                    const float* __restrict__ Wk,
                                                    const float* __restrict__ Wv,
                                                    short* __restrict__ wtf) {
    int idx = blockIdx.x * 256 + threadIdx.x;   // < 3*131072
    int w = idx >> 17;
    int rem = idx & 131071;
    int ks = rem >> 12;
    int r2 = rem & 4095;
    int nt = r2 >> 9;
    int r3 = r2 & 511;
    int lane = r3 >> 3, e = r3 & 7;
    int q4 = lane >> 4, l16 = lane & 15;
    int n = 16 * nt + l16;
    int k = 32 * ks + 8 * q4 + e;
    const float* W = (w == 0) ? Wq : (w == 1) ? Wk : Wv;
    wtf[idx] = f2bf(W[k * 128 + n]);
}

// ---------------------------------------------------------------------------
// Kernel 1 (fused q/k/v): C = A[16384x1024](f32) * W (+bias) -> bf16.
// v6: W comes DIRECT from the fragment-packed wtf (coalesced 1KB L2 hits,
// issued BEFORE the A-DMA so in-order vmcnt never drains HBM); only A goes
// through LDS (double-buffered, XOR-swizzled, conflict-free, 1 barrier per
// 64-k chunk). BM=64/BK=64 -> 32KB LDS; grid (256,3) = 768 blocks = exactly
// 3 blocks/CU, all co-resident, perfectly balanced (r5's 15% occupancy was
// grid imbalance at 384 blocks). 256 thr = 2x2 waves, wave = 32r x 64c.
// ---------------------------------------------------------------------------
__global__ __launch_bounds__(256, 3) void proj_kernel(const float* __restrict__ Q,
                                                      const float* __restrict__ K,
                                                      const float* __restrict__ V,
                                                      const short* __restrict__ wtf,
                                                      const float* __restrict__ bq,
                                                      const float* __restrict__ bk,
                                                      const float* __restrict__ bv,
                                                      short* __restrict__ qo,
                                                      short* __restrict__ ko,
                                                      short* __restrict__ vo) {
    alignas(16) __shared__ float Asl[2][64 * 64];  // 16KB/buf: [row][16 slots], pos=c^(r&15)
    const int t = threadIdx.x;                    // 0..255
    const int wv = t >> 6, L = t & 63;
    const int wm = wv >> 1, wn = wv & 1;          // 2x2 wave grid
    const int q4 = L >> 4, l16 = L & 15;
    const int which = blockIdx.y;
    const float* A = (which == 0) ? Q : (which == 1) ? K : V;
    const short* Wf = wtf + which * 131072;
    const float* bias = (which == 0) ? bq : (which == 1) ? bk : bv;
    const int m0 = blockIdx.x * 64;

    floatx4 acc[2][4];
#pragma unroll
    for (int rg = 0; rg < 2; rg++)
#pragma unroll
        for (int nt = 0; nt < 4; nt++) acc[rg][nt] = (floatx4)0.0f;

    auto stage = [&](int buf, int k0) {
        // A tile 64x64 f32 = 1024 slots16 / 256 thr = 4 issues.
        // Dest linear; source col pre-swizzled: LDS[r][c] = A[r][(c^(r&15))*4..]
#pragma unroll
        for (int j = 0; j < 4; j++) {
            int s = j * 256 + t;
            int r = s >> 4, c = (s & 15) ^ (r & 15);
            ldst16(A + (size_t)(m0 + r) * 1024 + k0 + (c << 2),
                   &Asl[buf][(j * 256 + 64 * wv) * 4]);
        }
    };

    stage(0, 0);                                  // prologue DMA

    for (int kc = 0; kc < 16; kc++) {
        const int cur = kc & 1;
        __syncthreads();                          // drains stage(kc)

        // B fragments for this chunk: coalesced 1KB L2 loads, issued FIRST
        // (older than next A-DMA -> consuming them never drains the DMA)
        short8 bfr[2][4];
#pragma unroll
        for (int ks = 0; ks < 2; ks++)
#pragma unroll
            for (int nt = 0; nt < 4; nt++)
                bfr[ks][nt] = *(const short8*)(Wf +
                    (((size_t)(2 * kc + ks) * 8 + 4 * wn + nt) * 64 + L) * 8);

        if (kc + 1 < 16) stage(cur ^ 1, (kc + 1) * 64);  // next chunk lands under compute

        // A-frags from LDS (conflict-free XOR layout) + convert
        short8 af[2][2];
#pragma unroll
        for (int rg = 0; rg < 2; rg++)
#pragma unroll
            for (int ks = 0; ks < 2; ks++) {
                int r = 32 * wm + 16 * rg + l16;  // r&15 == l16
                int c0 = 8 * ks + 2 * q4;
                float4 f0 = *(float4*)&Asl[cur][(r * 16 + (c0 ^ l16)) * 4];
                float4 f1 = *(float4*)&Asl[cur][(r * 16 + ((c0 + 1) ^ l16)) * 4];
                short8 v;
                v[0] = f2bf(f0.x); v[1] = f2bf(f0.y); v[2] = f2bf(f0.z); v[3] = f2bf(f0.w);
                v[4] = f2bf(f1.x); v[5] = f2bf(f1.y); v[6] = f2bf(f1.z); v[7] = f2bf(f1.w);
                af[rg][ks] = v;
            }
#pragma unroll
        for (int ks = 0; ks < 2; ks++)
#pragma unroll
            for (int nt = 0; nt < 4; nt++) {
                acc[0][nt] = MFMA16(af[0][ks], bfr[ks][nt], acc[0][nt]);
                acc[1][nt] = MFMA16(af[1][ks], bfr[ks][nt], acc[1][nt]);
            }
    }

#pragma unroll
    for (int rg = 0; rg < 2; rg++) {
        const int rbase = m0 + 32 * wm + 16 * rg + q4 * 4;  // C/D: row=(lane>>4)*4+r
#pragma unroll
        for (int nt = 0; nt < 4; nt++) {
            const int col = 64 * wn + 16 * nt + l16;        // C/D: col=lane&15
            float bvv = bias[col];
#pragma unroll
            for (int r = 0; r < 4; r++) {
                short h = f2bf(acc[rg][nt][r] + bvv);
                int grow = rbase + r;
                if (which == 0) {
                    qo[(size_t)grow * 128 + col] = h;
                } else if (which == 1) {
                    ko[(size_t)grow * 128 + col] = h;
                } else {
                    int bb = grow >> 11, s = grow & 2047;
                    vo[(size_t)bb * 262144 + (size_t)col * 2048 + s] = h;
                }
            }
        }
    }
}

// ---------------------------------------------------------------------------
// Kernel 2: flash attention, fixed-offset softmax (scores bounded; see r0).
// v6 = r1's structure (512 thr = 2 kv-pairs x 4 q-waves, K/V double-buffered
// via DMA, ONE barrier/iter, in-block pair merge) + batch->XCD swizzle
// (b = bid&7): consecutive block ids round-robin XCDs, so all 32 blocks of
// batch b land on XCD b and re-read only their own 1MB of K/V from local L2
// (8MB total working set would thrash the 4MB per-XCD L2 otherwise -> the
// ~97us L3-bound plateau of r0-r4). LDS 146KB, 1 block/CU = 8 waves.
// ---------------------------------------------------------------------------
__global__ __launch_bounds__(512, 2) void flash_kernel(const short* __restrict__ qw,
                                                       const short* __restrict__ kw,
                                                       const short* __restrict__ vw,
                                                       float* __restrict__ out) {
    alignas(16) __shared__ short Kls[2][2][64 * 128];   // [buf][pair], pos=c^(r&15)
    alignas(16) __shared__ short Vls[2][2][128 * 64];   // [buf][pair], pos=c^(r&7)
    alignas(16) __shared__ short Pl[2][64][72];         // [pair][q][kv] (+8 pad)
    const int t = threadIdx.x;                       // 0..511
    const int wvi = t >> 6, L = t & 63;
    const int pr = wvi >> 2, wq = wvi & 3;           // pair, wave-in-pair
    const int pt = t & 255;                          // thread-in-pair
    const int q4 = L >> 4, l16 = L & 15;
    const int bid = blockIdx.x;
    const int b = bid & 7, bq = bid >> 3;            // batch->XCD affinity
    const short* qp = qw + (size_t)b * 262144 + (size_t)bq * 64 * 128;
    const short* kp = kw + (size_t)b * 262144;
    const short* vp = vw + (size_t)b * 262144;

    // Q-frags: wave-private, direct from global (row = 16*wq + l16)
    short8 qf[4];
#pragma unroll
    for (int ks = 0; ks < 4; ks++)
        qf[ks] = *(const short8*)(qp + (16 * wq + l16) * 128 + ks * 32 + q4 * 8);

    floatx4 oacc[8];
#pragma unroll
    for (int dt = 0; dt < 8; dt++) oacc[dt] = (floatx4)0.0f;
    float ps[4] = {0.f, 0.f, 0.f, 0.f};              // distributed row sums
    const float SL = (float)(0.08838834764831845 * 1.4426950408889634); // 1/sqrt(128)*log2(e)

    auto stage = [&](int buf, int kt) {
        const int kv0 = pr * 1024 + kt * 64;
        // K-tile 64x128 (16KB, pair-private): 1024 slots / 256 thr = 4 issues
#pragma unroll
        for (int j = 0; j < 4; j++) {
            int s = j * 256 + pt;
            int r = s >> 4, c = (s & 15) ^ (r & 15);
            ldst16(kp + (size_t)(kv0 + r) * 128 + c * 8,
                   &Kls[buf][pr][(j * 256 + 64 * wq) * 8]);
        }
        // V-tile 128x64 (pre-transposed vt): 1024 slots
#pragma unroll
        for (int j = 0; j < 4; j++) {
            int s = j * 256 + pt;
            int r = s >> 3, c = (s & 7) ^ (r & 7);
            ldst16(vp + (size_t)r * 2048 + kv0 + c * 8,
                   &Vls[buf][pr][(j * 256 + 64 * wq) * 8]);
        }
    };

    stage(0, 0);                                     // prologue DMA

    for (int kt = 0; kt < 16; kt++) {
        const int cur = kt & 1;
        // single barrier: drains stage(kt) DMA (vmcnt(0)) + releases buf cur^1
        __syncthreads();
        if (kt + 1 < 16) stage(cur ^ 1, kt + 1);     // next-tile DMA under compute

        // S = Q K^T  (16 q-rows x 64 kv per wave)
        floatx4 sa[4];
#pragma unroll
        for (int nt = 0; nt < 4; nt++) {
            sa[nt] = (floatx4)0.0f;
#pragma unroll
            for (int ks = 0; ks < 4; ks++) {
                short8 bfr = *(short8*)&Kls[cur][pr][(16 * nt + l16) * 128 + ((4 * ks + q4) ^ l16) * 8];
                sa[nt] = MFMA16(qf[ks], bfr, sa[nt]);
            }
        }

        // fixed-offset softmax: p = exp2(s*SL - 4); accumulate per-lane sums
#pragma unroll
        for (int nt = 0; nt < 4; nt++) {
#pragma unroll
            for (int r = 0; r < 4; r++) {
                float pv = __builtin_amdgcn_exp2f(sa[nt][r] * SL - 4.0f);
                ps[r] += pv;
                Pl[pr][16 * wq + q4 * 4 + r][16 * nt + l16] = f2bf(pv);
            }
        }

        // O += P V
        short8 pf0 = *(short8*)&Pl[pr][16 * wq + l16][q4 * 8];
        short8 pf1 = *(short8*)&Pl[pr][16 * wq + l16][32 + q4 * 8];
#pragma unroll
        for (int dt = 0; dt < 8; dt++) {
            short8 v0 = *(short8*)&Vls[cur][pr][(16 * dt + l16) * 64 + (q4 ^ (l16 & 7)) * 8];
            short8 v1 = *(short8*)&Vls[cur][pr][(16 * dt + l16) * 64 + ((4 + q4) ^ (l16 & 7)) * 8];
            oacc[dt] = MFMA16(pf0, v0, oacc[dt]);
            oacc[dt] = MFMA16(pf1, v1, oacc[dt]);
        }
    }

    // one shuffle-reduce at the end: sum ps over the 16 col-lanes per row group
#pragma unroll
    for (int r = 0; r < 4; r++)
#pragma unroll
        for (int off = 1; off <= 8; off <<= 1)
            ps[r] += __shfl_xor(ps[r], off, 64);

    // ---- merge the two kv-halves (plain sums; no max needed) ----
    __syncthreads();
    float* Om = (float*)&Kls[0][0][0];  // 64x128 f32 = 32KB (= Kls buf0)
    float* Lm = (float*)&Vls[0][0][0];  // 64 floats
    if (pr == 1) {
#pragma unroll
        for (int dt = 0; dt < 8; dt++)
#pragma unroll
            for (int r = 0; r < 4; r++)
                Om[(16 * wq + q4 * 4 + r) * 128 + 16 * dt + l16] = oacc[dt][r];
        if (l16 == 0)
#pragma unroll
            for (int r = 0; r < 4; r++)
                Lm[16 * wq + q4 * 4 + r] = ps[r];
    }
    __syncthreads();
    if (pr == 0) {
        float inv[4];
#pragma unroll
        for (int r = 0; r < 4; r++)
            inv[r] = 1.0f / (ps[r] + Lm[16 * wq + q4 * 4 + r]);
#pragma unroll
        for (int dt = 0; dt < 8; dt++) {
#pragma unroll
            for (int r = 0; r < 4; r++) {
                int row = 16 * wq + q4 * 4 + r;
                int qrow = bq * 64 + row;
                out[((size_t)b * 2048 + qrow) * 128 + 16 * dt + l16] =
                    (oacc[dt][r] + Om[row * 128 + 16 * dt + l16]) * inv[r];
            }
        }
    }
}

extern "C" void kernel_launch(void* const* d_in, const int* in_sizes, int n_in,
                              void* d_out, int out_size, void* d_ws, size_t ws_size,
                              hipStream_t stream) {
    const float* query = (const float*)d_in[0];
    const float* key   = (const float*)d_in[1];
    const float* value = (const float*)d_in[2];
    const float* Wq    = (const float*)d_in[3];
    const float* bq    = (const float*)d_in[4];
    const float* Wk    = (const float*)d_in[5];
    const float* bk    = (const float*)d_in[6];
    const float* Wv    = (const float*)d_in[7];
    const float* bv    = (const float*)d_in[8];
    float* out = (float*)d_out;

    // ws layout (shorts): wtf[3][32][8][64][8] | q[16384][128] | k[16384][128] | vt[8][128][2048]
    short* wtf = (short*)d_ws;
    short* qws = wtf + 3 * 131072;
    short* kws = qws + 16384 * 128;
    short* vws = kws + 16384 * 128;

    wconv_kernel<<<1536, 256, 0, stream>>>(Wq, Wk, Wv, wtf);
    proj_kernel<<<dim3(256, 3), 256, 0, stream>>>(query, key, value, wtf,
                                                  bq, bk, bv, qws, kws, vws);
    flash_kernel<<<256, 512, 0, stream>>>(qws, kws, vws, out);
}